// Round 8
// baseline (466.638 us; speedup 1.0000x reference)
//
#include <hip/hip_runtime.h>
#include <math.h>

// z: (B=16, C=512, H=64, W=64) f32 ; codebook: (K=2048, D=64)
// tokens N = B*H*W = 65536; fused kernel: 64 tokens/block, grid 1024.

typedef __attribute__((address_space(1))) const unsigned int* gas_ptr;
typedef __attribute__((address_space(3))) unsigned int* las_ptr;
#define GLD_LDS16(gsrc, ldst) \
  __builtin_amdgcn_global_load_lds((gas_ptr)(const void*)(gsrc), \
                                   (las_ptr)(void*)(ldst), 16, 0, 0)

// ---------------- prep kernels ----------------

// wiT[c][d] = g[d] * v[d][c] / ||v[d,:]||
__global__ void k_prep_wi(const float* __restrict__ v, const float* __restrict__ g,
                          float* __restrict__ wiT){
  const int d = blockIdx.x;          // 64
  const int tid = threadIdx.x;       // 256
  float s = 0.f;
  for (int c = tid; c < 512; c += 256){ float x = v[d*512+c]; s = fmaf(x,x,s); }
  __shared__ float red[4];
  #pragma unroll
  for (int o = 32; o > 0; o >>= 1) s += __shfl_down(s, o);
  if ((tid & 63) == 0) red[tid >> 6] = s;
  __syncthreads();
  const float nrm = sqrtf(red[0]+red[1]+red[2]+red[3]);
  const float gd = g[d];
  for (int c = tid; c < 512; c += 256) wiT[c*64 + d] = gd * v[d*512+c] / nrm;
}

__global__ void k_prep_wo(const float* __restrict__ v, const float* __restrict__ g,
                          float* __restrict__ wot){
  const int c = blockIdx.x;          // 512
  const int d = threadIdx.x;         // 64
  const float x = v[c*64+d];
  float s = x*x;
  #pragma unroll
  for (int o = 32; o > 0; o >>= 1) s += __shfl_down(s, o);
  const float nrm = __shfl(sqrtf(s), 0);
  wot[d*512 + c] = g[c] * x / nrm;   // WoT[d][c]
}

// Table[k][c] = sum_d cb[k][d]*WoT[d][c] + ob[c];  ne[k] = ||cb[k]||^2;
// cbm2[k][d] = -2*cb[k][d]  (prescaled, row-major; -2*x exact in fp32)
__global__ void k_table(const float* __restrict__ cbk, const float* __restrict__ wot,
                        const float* __restrict__ ob, float* __restrict__ table,
                        float* __restrict__ ne, float* __restrict__ cbm2){
  const int k = blockIdx.x;          // 2048
  const int tid = threadIdx.x;       // 512
  __shared__ float e[64];
  if (tid < 64) e[tid] = cbk[k*64 + tid];
  __syncthreads();
  if (tid < 64){
    float x = e[tid];
    cbm2[(size_t)k*64 + tid] = -2.0f * x;
    float s = x*x;
    #pragma unroll
    for (int o = 32; o > 0; o >>= 1) s += __shfl_down(s, o);
    if (tid == 0) ne[k] = s;
  }
  const int c = tid;
  float acc = ob[c];
  #pragma unroll 16
  for (int d = 0; d < 64; d++) acc = fmaf(e[d], wot[d*512 + c], acc);
  table[(size_t)k*512 + c] = acc;
}

// ---------------- fused main ----------------
// 64 tokens/block, grid 1024 (4 blocks/CU; LDS 35KB, ~110 VGPR under cap 128).
// Phase 1: z_e = Wi@z + b into ze_s (DMA-double-buffered staging).
// Phase 2: BARRIER-FREE: thread (t=tid&63, q=tid>>6) keeps ze[64] in VGPRs and
// scans codes [q*512, q*512+512) with wave-uniform broadcast loads of cbm2.
__global__ __launch_bounds__(256, 2) void k_main(
    const float* __restrict__ z, const float* __restrict__ wiT,
    const float* __restrict__ inb, const float* __restrict__ cbm2,
    const float* __restrict__ cbk, const float* __restrict__ ne,
    const float* __restrict__ table, float* __restrict__ out,
    float* __restrict__ oidx, double* __restrict__ loss)
{
  __shared__ __align__(16) float ze_s[64*68];     // 17408 B [d][t], pad 68
  __shared__ __align__(16) float rgb[2*2176];     // 17408 B: phase1 staging / reduce
  __shared__ int bidx_s[64];

  const int tid  = threadIdx.x;
  const int w    = tid >> 6;         // wave 0..3
  const int lane = tid & 63;
  const int t0   = blockIdx.x << 6;  // 64 tokens
  const int b    = t0 >> 12;
  const int hw0  = t0 & 4095;
  const float* zb = z + ((size_t)b << 21) + hw0;

  const int tg  = tid & 15;          // phase1 token group: tokens tg*4..+3
  const int dgp = tid >> 4;          // phase1: d = dgp*4..+3

  // ---------------- phase 1: in_proj ----------------
  const int srow = w*4 + (lane >> 4);      // 0..15
  const int scol = (lane & 15) << 2;       // 0..60

  float acc1[4][4];
  #pragma unroll
  for (int i = 0; i < 4; i++)
    #pragma unroll
    for (int j = 0; j < 4; j++) acc1[i][j] = 0.f;

  GLD_LDS16(zb + (size_t)srow*4096 + scol,  &rgb[0*2176 + w*256]);
  GLD_LDS16(wiT + srow*64 + scol,           &rgb[0*2176 + 1024 + w*256]);
  __syncthreads();

  for (int c = 0; c < 32; c++){
    const int buf = c & 1;
    if (c < 31){
      const int c0n = (c+1) << 4;
      GLD_LDS16(zb + (size_t)(c0n + srow)*4096 + scol, &rgb[(buf^1)*2176 + w*256]);
      GLD_LDS16(wiT + (c0n + srow)*64 + scol,          &rgb[(buf^1)*2176 + 1024 + w*256]);
    }
    const float* zc = &rgb[buf*2176];
    const float* wc = &rgb[buf*2176 + 1024];
    #pragma unroll 4
    for (int cc = 0; cc < 16; cc++){
      const float4 ta = *(const float4*)&zc[cc*64 + tg*4];
      const float4 wv = *(const float4*)&wc[cc*64 + dgp*4];
      acc1[0][0]=fmaf(ta.x,wv.x,acc1[0][0]); acc1[0][1]=fmaf(ta.y,wv.x,acc1[0][1]);
      acc1[0][2]=fmaf(ta.z,wv.x,acc1[0][2]); acc1[0][3]=fmaf(ta.w,wv.x,acc1[0][3]);
      acc1[1][0]=fmaf(ta.x,wv.y,acc1[1][0]); acc1[1][1]=fmaf(ta.y,wv.y,acc1[1][1]);
      acc1[1][2]=fmaf(ta.z,wv.y,acc1[1][2]); acc1[1][3]=fmaf(ta.w,wv.y,acc1[1][3]);
      acc1[2][0]=fmaf(ta.x,wv.z,acc1[2][0]); acc1[2][1]=fmaf(ta.y,wv.z,acc1[2][1]);
      acc1[2][2]=fmaf(ta.z,wv.z,acc1[2][2]); acc1[2][3]=fmaf(ta.w,wv.z,acc1[2][3]);
      acc1[3][0]=fmaf(ta.x,wv.w,acc1[3][0]); acc1[3][1]=fmaf(ta.y,wv.w,acc1[3][1]);
      acc1[3][2]=fmaf(ta.z,wv.w,acc1[3][2]); acc1[3][3]=fmaf(ta.w,wv.w,acc1[3][3]);
    }
    __syncthreads();
  }

  // epilogue: + in_b -> ze_s[d][t]
  #pragma unroll
  for (int i = 0; i < 4; i++){
    const int d = dgp*4 + i;
    const float bd = inb[d];
    float4 o = {acc1[i][0]+bd, acc1[i][1]+bd, acc1[i][2]+bd, acc1[i][3]+bd};
    *(float4*)&ze_s[d*68 + tg*4] = o;
  }
  __syncthreads();                   // ze_s complete

  // ---------------- phase 2: barrier-free argmin ----------------
  const int q = __builtin_amdgcn_readfirstlane(tid >> 6);  // wave-uniform quarter
  const int t = tid & 63;            // this thread's token

  float ze_r[64];
  #pragma unroll
  for (int d = 0; d < 64; d++) ze_r[d] = ze_s[d*68 + t];   // conflict-free columns

  float best = INFINITY; int bi = 0;
  const float* __restrict__ cq  = cbm2 + ((size_t)q << 9) * 64;
  const float* __restrict__ neq = ne + (q << 9);

  for (int kk = 0; kk < 512; kk += 2){
    const float2 nv = *(const float2*)&neq[kk];
    const float* r0 = cq + (size_t)kk * 64;
    float d0 = nv.x, d1 = nv.y;
    #pragma unroll
    for (int j = 0; j < 16; j++){
      const float4 a = *(const float4*)(r0 + 4*j);
      const float4 bq = *(const float4*)(r0 + 64 + 4*j);
      const int db = 4*j;
      d0 = fmaf(ze_r[db  ], a.x, d0);
      d0 = fmaf(ze_r[db+1], a.y, d0);
      d0 = fmaf(ze_r[db+2], a.z, d0);
      d0 = fmaf(ze_r[db+3], a.w, d0);
      d1 = fmaf(ze_r[db  ], bq.x, d1);
      d1 = fmaf(ze_r[db+1], bq.y, d1);
      d1 = fmaf(ze_r[db+2], bq.z, d1);
      d1 = fmaf(ze_r[db+3], bq.w, d1);
    }
    const int k = (q << 9) + kk;
    if (d0 < best){ best = d0; bi = k; }
    if (d1 < best){ best = d1; bi = k + 1; }
  }

  // cross-quarter argmin reduce: candidates for token t in threads {t,64+t,...}
  float* rb = rgb;                   // [4][64]
  int*   ri = (int*)(rgb + 256);     // [4][64]
  rb[q*64 + t] = best;
  ri[q*64 + t] = bi;
  __syncthreads();

  if (tid < 64){
    float bv = rb[t]; int bfin = ri[t];
    #pragma unroll
    for (int qq = 1; qq < 4; qq++){
      const float vq = rb[qq*64 + t]; const int iq = ri[qq*64 + t];
      if (vq < bv){ bv = vq; bfin = iq; }   // q asc = k asc; strict < keeps lower k
    }
    bidx_s[t] = bfin;
    oidx[t0 + t] = (float)bfin;
    // loss: sum_d (z_e - e)^2, d ascending (ze_r == ze_s column, exact)
    float myloss = 0.f;
    const float* e = cbk + (size_t)bfin * 64;
    #pragma unroll 8
    for (int d = 0; d < 64; d++){
      const float diff = ze_r[d] - e[d];
      myloss = fmaf(diff, diff, myloss);
    }
    #pragma unroll
    for (int o = 32; o > 0; o >>= 1) myloss += __shfl_down(myloss, o);
    if (t == 0) atomicAdd(loss, (double)myloss);
  }
  __syncthreads();

  // output gather: out[b][c][hw] = Table[idx][c]
  {
    const int tl = tid & 63, cg = tid >> 6;       // 4 c-groups x 128 c
    const int myk = bidx_s[tl];
    const float* trow = table + ((size_t)myk << 9) + cg*128;
    float* ob = out + (((size_t)b) << 21) + hw0 + tl;
    #pragma unroll 4
    for (int ci = 0; ci < 32; ci++){
      const float4 v = *(const float4*)(trow + ci*4);
      const size_t cbase = (size_t)(cg*128 + ci*4) << 12;
      ob[cbase        ] = v.x;
      ob[cbase +  4096] = v.y;
      ob[cbase +  8192] = v.z;
      ob[cbase + 12288] = v.w;
    }
  }
}

__global__ void k_finish(const double* __restrict__ loss, float* __restrict__ oloss){
  *oloss = (float)(1.25 * (*loss) / 4194304.0);   // 1.25 * mean over B*D*H*W
}

// ---------------- launch ----------------

extern "C" void kernel_launch(void* const* d_in, const int* in_sizes, int n_in,
                              void* d_out, int out_size, void* d_ws, size_t ws_size,
                              hipStream_t stream) {
  const float* z   = (const float*)d_in[0];
  const float* cbk = (const float*)d_in[1];
  const float* inv = (const float*)d_in[2];
  const float* ing = (const float*)d_in[3];
  const float* inb = (const float*)d_in[4];
  const float* ov  = (const float*)d_in[5];
  const float* og  = (const float*)d_in[6];
  const float* ob  = (const float*)d_in[7];

  float* ws    = (float*)d_ws;
  float* wiT   = ws;                       // [512][64]
  float* wot   = ws + 32768;               // [64][512]
  float* table = ws + 65536;               // [2048][512]
  float* ne    = ws + 65536 + 1048576;     // [2048]
  double* loss = (double*)(ws + 1116160);  // 8B aligned
  float* cbm2  = ws + 1179648;             // [2048][64] = 512 KB

  float* out   = (float*)d_out;            // [16][512][4096]
  float* oidx  = out + 33554432;           // [65536]
  float* oloss = out + 33619968;           // scalar

  hipMemsetAsync(loss, 0, sizeof(double), stream);
  k_prep_wi<<<64, 256, 0, stream>>>(inv, ing, wiT);
  k_prep_wo<<<512, 64, 0, stream>>>(ov, og, wot);
  k_table<<<2048, 512, 0, stream>>>(cbk, wot, ob, table, ne, cbm2);
  k_main<<<1024, 256, 0, stream>>>(z, wiT, inb, cbm2, cbk, ne, table, out, oidx, loss);
  k_finish<<<1, 1, 0, stream>>>(loss, oloss);
}

// Round 9
// 452.403 us; speedup vs baseline: 1.0315x; 1.0315x over previous
//
#include <hip/hip_runtime.h>
#include <math.h>

// z: (B=16, C=512, H=64, W=64) f32 ; codebook: (K=2048, D=64)
// tokens N = B*H*W = 65536; fused kernel: 64 tokens/block, grid 1024.

typedef __attribute__((address_space(1))) const unsigned int* gas_ptr;
typedef __attribute__((address_space(3))) unsigned int* las_ptr;
#define GLD_LDS16(gsrc, ldst) \
  __builtin_amdgcn_global_load_lds((gas_ptr)(const void*)(gsrc), \
                                   (las_ptr)(void*)(ldst), 16, 0, 0)

// ---------------- prep kernels ----------------

// wiT[c][d] = g[d] * v[d][c] / ||v[d,:]||
__global__ void k_prep_wi(const float* __restrict__ v, const float* __restrict__ g,
                          float* __restrict__ wiT){
  const int d = blockIdx.x;          // 64
  const int tid = threadIdx.x;       // 256
  float s = 0.f;
  for (int c = tid; c < 512; c += 256){ float x = v[d*512+c]; s = fmaf(x,x,s); }
  __shared__ float red[4];
  #pragma unroll
  for (int o = 32; o > 0; o >>= 1) s += __shfl_down(s, o);
  if ((tid & 63) == 0) red[tid >> 6] = s;
  __syncthreads();
  const float nrm = sqrtf(red[0]+red[1]+red[2]+red[3]);
  const float gd = g[d];
  for (int c = tid; c < 512; c += 256) wiT[c*64 + d] = gd * v[d*512+c] / nrm;
}

__global__ void k_prep_wo(const float* __restrict__ v, const float* __restrict__ g,
                          float* __restrict__ wot){
  const int c = blockIdx.x;          // 512
  const int d = threadIdx.x;         // 64
  const float x = v[c*64+d];
  float s = x*x;
  #pragma unroll
  for (int o = 32; o > 0; o >>= 1) s += __shfl_down(s, o);
  const float nrm = __shfl(sqrtf(s), 0);
  wot[d*512 + c] = g[c] * x / nrm;   // WoT[d][c]
}

// Table[k][c] = sum_d cb[k][d]*WoT[d][c] + ob[c];  ne[k] = ||cb[k]||^2;
// cbm2[k][d] = -2*cb[k][d]  (prescaled, row-major; -2*x exact in fp32)
__global__ void k_table(const float* __restrict__ cbk, const float* __restrict__ wot,
                        const float* __restrict__ ob, float* __restrict__ table,
                        float* __restrict__ ne, float* __restrict__ cbm2){
  const int k = blockIdx.x;          // 2048
  const int tid = threadIdx.x;       // 512
  __shared__ float e[64];
  if (tid < 64) e[tid] = cbk[k*64 + tid];
  __syncthreads();
  if (tid < 64){
    float x = e[tid];
    cbm2[(size_t)k*64 + tid] = -2.0f * x;
    float s = x*x;
    #pragma unroll
    for (int o = 32; o > 0; o >>= 1) s += __shfl_down(s, o);
    if (tid == 0) ne[k] = s;
  }
  const int c = tid;
  float acc = ob[c];
  #pragma unroll 16
  for (int d = 0; d < 64; d++) acc = fmaf(e[d], wot[d*512 + c], acc);
  table[(size_t)k*512 + c] = acc;
}

// ---------------- fused main ----------------
// 64 tokens/block, grid 1024 (4 blocks/CU; LDS 35KB).
// Phase 1: z_e = Wi@z + b into ze_s (DMA-double-buffered staging).
// Phase 2: BARRIER-FREE: thread (t=tid&63, q=tid>>6) keeps ze[64] in VGPRs and
// scans codes [q*512, q*512+512) with wave-uniform broadcast loads of cbm2.
// RULE-#20 GUARD: ze_r must ONLY be indexed from fully-unrolled loops (static
// indices). r8's '#pragma unroll 8' loss loop demoted ze_r to scratch
// (VGPR 56, +65MB WRITE). Loss now reads ze_s (LDS) instead.
__global__ __launch_bounds__(256, 2) void k_main(
    const float* __restrict__ z, const float* __restrict__ wiT,
    const float* __restrict__ inb, const float* __restrict__ cbm2,
    const float* __restrict__ cbk, const float* __restrict__ ne,
    const float* __restrict__ table, float* __restrict__ out,
    float* __restrict__ oidx, double* __restrict__ loss)
{
  __shared__ __align__(16) float ze_s[64*68];     // 17408 B [d][t], pad 68
  __shared__ __align__(16) float rgb[2*2176];     // 17408 B: phase1 staging / reduce
  __shared__ int bidx_s[64];

  const int tid  = threadIdx.x;
  const int w    = tid >> 6;         // wave 0..3
  const int lane = tid & 63;
  const int t0   = blockIdx.x << 6;  // 64 tokens
  const int b    = t0 >> 12;
  const int hw0  = t0 & 4095;
  const float* zb = z + ((size_t)b << 21) + hw0;

  const int tg  = tid & 15;          // phase1 token group: tokens tg*4..+3
  const int dgp = tid >> 4;          // phase1: d = dgp*4..+3

  // ---------------- phase 1: in_proj ----------------
  const int srow = w*4 + (lane >> 4);      // 0..15
  const int scol = (lane & 15) << 2;       // 0..60

  float acc1[4][4];
  #pragma unroll
  for (int i = 0; i < 4; i++)
    #pragma unroll
    for (int j = 0; j < 4; j++) acc1[i][j] = 0.f;

  GLD_LDS16(zb + (size_t)srow*4096 + scol,  &rgb[0*2176 + w*256]);
  GLD_LDS16(wiT + srow*64 + scol,           &rgb[0*2176 + 1024 + w*256]);
  __syncthreads();

  for (int c = 0; c < 32; c++){
    const int buf = c & 1;
    if (c < 31){
      const int c0n = (c+1) << 4;
      GLD_LDS16(zb + (size_t)(c0n + srow)*4096 + scol, &rgb[(buf^1)*2176 + w*256]);
      GLD_LDS16(wiT + (c0n + srow)*64 + scol,          &rgb[(buf^1)*2176 + 1024 + w*256]);
    }
    const float* zc = &rgb[buf*2176];
    const float* wc = &rgb[buf*2176 + 1024];
    #pragma unroll 4
    for (int cc = 0; cc < 16; cc++){
      const float4 ta = *(const float4*)&zc[cc*64 + tg*4];
      const float4 wv = *(const float4*)&wc[cc*64 + dgp*4];
      acc1[0][0]=fmaf(ta.x,wv.x,acc1[0][0]); acc1[0][1]=fmaf(ta.y,wv.x,acc1[0][1]);
      acc1[0][2]=fmaf(ta.z,wv.x,acc1[0][2]); acc1[0][3]=fmaf(ta.w,wv.x,acc1[0][3]);
      acc1[1][0]=fmaf(ta.x,wv.y,acc1[1][0]); acc1[1][1]=fmaf(ta.y,wv.y,acc1[1][1]);
      acc1[1][2]=fmaf(ta.z,wv.y,acc1[1][2]); acc1[1][3]=fmaf(ta.w,wv.y,acc1[1][3]);
      acc1[2][0]=fmaf(ta.x,wv.z,acc1[2][0]); acc1[2][1]=fmaf(ta.y,wv.z,acc1[2][1]);
      acc1[2][2]=fmaf(ta.z,wv.z,acc1[2][2]); acc1[2][3]=fmaf(ta.w,wv.z,acc1[2][3]);
      acc1[3][0]=fmaf(ta.x,wv.w,acc1[3][0]); acc1[3][1]=fmaf(ta.y,wv.w,acc1[3][1]);
      acc1[3][2]=fmaf(ta.z,wv.w,acc1[3][2]); acc1[3][3]=fmaf(ta.w,wv.w,acc1[3][3]);
    }
    __syncthreads();
  }

  // epilogue: + in_b -> ze_s[d][t]
  #pragma unroll
  for (int i = 0; i < 4; i++){
    const int d = dgp*4 + i;
    const float bd = inb[d];
    float4 o = {acc1[i][0]+bd, acc1[i][1]+bd, acc1[i][2]+bd, acc1[i][3]+bd};
    *(float4*)&ze_s[d*68 + tg*4] = o;
  }
  __syncthreads();                   // ze_s complete

  // ---------------- phase 2: barrier-free argmin ----------------
  const int q = __builtin_amdgcn_readfirstlane(tid >> 6);  // wave-uniform quarter
  const int t = tid & 63;            // this thread's token

  float ze_r[64];
  #pragma unroll
  for (int d = 0; d < 64; d++) ze_r[d] = ze_s[d*68 + t];   // static idx, 2-way banks

  float best = INFINITY; int bi = 0;
  const float* __restrict__ cq  = cbm2 + ((size_t)q << 9) * 64;
  const float* __restrict__ neq = ne + (q << 9);

  for (int kk = 0; kk < 512; kk += 2){
    const float2 nv = *(const float2*)&neq[kk];
    const float* r0 = cq + (size_t)kk * 64;
    float d0 = nv.x, d1 = nv.y;
    #pragma unroll
    for (int j = 0; j < 16; j++){
      const float4 a = *(const float4*)(r0 + 4*j);
      const float4 bq = *(const float4*)(r0 + 64 + 4*j);
      const int db = 4*j;
      d0 = fmaf(ze_r[db  ], a.x, d0);
      d0 = fmaf(ze_r[db+1], a.y, d0);
      d0 = fmaf(ze_r[db+2], a.z, d0);
      d0 = fmaf(ze_r[db+3], a.w, d0);
      d1 = fmaf(ze_r[db  ], bq.x, d1);
      d1 = fmaf(ze_r[db+1], bq.y, d1);
      d1 = fmaf(ze_r[db+2], bq.z, d1);
      d1 = fmaf(ze_r[db+3], bq.w, d1);
    }
    const int k = (q << 9) + kk;
    if (d0 < best){ best = d0; bi = k; }
    if (d1 < best){ best = d1; bi = k + 1; }
  }

  // cross-quarter argmin reduce: candidates for token t in threads {t,64+t,...}
  float* rb = rgb;                   // [4][64]
  int*   ri = (int*)(rgb + 256);     // [4][64]
  rb[q*64 + t] = best;
  ri[q*64 + t] = bi;
  __syncthreads();

  if (tid < 64){
    float bv = rb[t]; int bfin = ri[t];
    #pragma unroll
    for (int qq = 1; qq < 4; qq++){
      const float vq = rb[qq*64 + t]; const int iq = ri[qq*64 + t];
      if (vq < bv){ bv = vq; bfin = iq; }   // q asc = k asc; strict < keeps lower k
    }
    bidx_s[t] = bfin;
    oidx[t0 + t] = (float)bfin;
    // loss: sum_d (z_e - e)^2, d ascending — reads ze_s (LDS), NOT ze_r,
    // so partial unroll's runtime index cannot demote ze_r to scratch.
    float myloss = 0.f;
    const float* e = cbk + (size_t)bfin * 64;
    #pragma unroll 8
    for (int d = 0; d < 64; d++){
      const float diff = ze_s[d*68 + t] - e[d];
      myloss = fmaf(diff, diff, myloss);
    }
    #pragma unroll
    for (int o = 32; o > 0; o >>= 1) myloss += __shfl_down(myloss, o);
    if (t == 0) atomicAdd(loss, (double)myloss);
  }
  __syncthreads();

  // output gather: out[b][c][hw] = Table[idx][c]
  {
    const int tl = tid & 63, cg = tid >> 6;       // 4 c-groups x 128 c
    const int myk = bidx_s[tl];
    const float* trow = table + ((size_t)myk << 9) + cg*128;
    float* ob = out + (((size_t)b) << 21) + hw0 + tl;
    #pragma unroll 4
    for (int ci = 0; ci < 32; ci++){
      const float4 v = *(const float4*)(trow + ci*4);
      const size_t cbase = (size_t)(cg*128 + ci*4) << 12;
      ob[cbase        ] = v.x;
      ob[cbase +  4096] = v.y;
      ob[cbase +  8192] = v.z;
      ob[cbase + 12288] = v.w;
    }
  }
}

__global__ void k_finish(const double* __restrict__ loss, float* __restrict__ oloss){
  *oloss = (float)(1.25 * (*loss) / 4194304.0);   // 1.25 * mean over B*D*H*W
}

// ---------------- launch ----------------

extern "C" void kernel_launch(void* const* d_in, const int* in_sizes, int n_in,
                              void* d_out, int out_size, void* d_ws, size_t ws_size,
                              hipStream_t stream) {
  const float* z   = (const float*)d_in[0];
  const float* cbk = (const float*)d_in[1];
  const float* inv = (const float*)d_in[2];
  const float* ing = (const float*)d_in[3];
  const float* inb = (const float*)d_in[4];
  const float* ov  = (const float*)d_in[5];
  const float* og  = (const float*)d_in[6];
  const float* ob  = (const float*)d_in[7];

  float* ws    = (float*)d_ws;
  float* wiT   = ws;                       // [512][64]
  float* wot   = ws + 32768;               // [64][512]
  float* table = ws + 65536;               // [2048][512]
  float* ne    = ws + 65536 + 1048576;     // [2048]
  double* loss = (double*)(ws + 1116160);  // 8B aligned
  float* cbm2  = ws + 1179648;             // [2048][64] = 512 KB

  float* out   = (float*)d_out;            // [16][512][4096]
  float* oidx  = out + 33554432;           // [65536]
  float* oloss = out + 33619968;           // scalar

  hipMemsetAsync(loss, 0, sizeof(double), stream);
  k_prep_wi<<<64, 256, 0, stream>>>(inv, ing, wiT);
  k_prep_wo<<<512, 64, 0, stream>>>(ov, og, wot);
  k_table<<<2048, 512, 0, stream>>>(cbk, wot, ob, table, ne, cbm2);
  k_main<<<1024, 256, 0, stream>>>(z, wiT, inb, cbm2, cbk, ne, table, out, oidx, loss);
  k_finish<<<1, 1, 0, stream>>>(loss, oloss);
}